// Round 1
// baseline (416.446 us; speedup 1.0000x reference)
//
#include <hip/hip_runtime.h>
#include <math.h>

#define NATOMS 122880
#define BATCH 4096
#define EPS 1e-3f

// Degree-block offsets (cumsum of COUNTS) and tile (32-atom) cumulative table.
__constant__ int d_OFFS[12] = {0,1024,25600,62464,99328,119808,121856,122368,122624,122752,122816,122880};
__constant__ int d_TCUM[12] = {0,32,800,1952,3104,3744,3808,3824,3832,3836,3838,3840};

struct Adj { const int* p[10]; };

__device__ inline void atomicMaxF(float* addr, float val) {
    if (val >= 0.f) {
        // map -0.0 -> +0.0 so the int-max path orders correctly
        atomicMax((int*)addr, __float_as_int(val == 0.f ? 0.f : val));
    } else {
        // negative floats: larger float == smaller unsigned bit pattern
        atomicMin((unsigned int*)addr, __float_as_uint(val));
    }
}

__global__ __launch_bounds__(256)
void init_seg(float* __restrict__ segS, float* __restrict__ segM) {
    int i = blockIdx.x * 256 + threadIdx.x;   // grid sized exactly 4096*128
    segS[i] = 0.f;
    segM[i] = __int_as_float(0xFF800000);     // -inf
}

// Graph conv for one 32-atom tile of a single degree block.
// out[row][f] = bn(tanh(rel@Wr + self@Ws + bias))
template<int F, int FPAD>
__global__ __launch_bounds__(256)
void conv_kernel(const float* __restrict__ x, const float* __restrict__ W,
                 const float* __restrict__ b,
                 const float* __restrict__ g, const float* __restrict__ beta,
                 const float* __restrict__ mean, const float* __restrict__ var,
                 Adj adj, float* __restrict__ out)
{
    __shared__ float s_self[32][FPAD];
    __shared__ float s_rel[32][FPAD];
    __shared__ int   s_adj[320];

    const int tid = threadIdx.x;
    const int bx  = blockIdx.x;
    int d = 0;
    #pragma unroll
    for (int i = 1; i <= 10; ++i) if (bx >= d_TCUM[i]) d = i;
    const int tile = bx - d_TCUM[d];
    const int row0 = d_OFFS[d] + tile * 32;

    if (d > 0) {
        const int* ap = adj.p[d-1] + (size_t)tile * 32 * d;
        for (int e = tid; e < 32 * d; e += 256) s_adj[e] = ap[e];
    }
    __syncthreads();

    // Stage self rows and neighbor-sum rows (d==0 -> s_rel = 0 automatically).
    for (int e = tid; e < 32 * F; e += 256) {
        int a = e / F, k = e - a * F;
        s_self[a][k] = x[(size_t)(row0 + a) * F + k];
        float sum = 0.f;
        for (int j = 0; j < d; ++j) sum += x[(size_t)s_adj[a*d + j] * F + k];
        s_rel[a][k] = sum;
    }
    __syncthreads();

    const int w = tid >> 6, f = tid & 63;
    const float* Wr; const float* Ws; float bias;
    if (d > 0) {
        Wr = W + (size_t)(2*d - 2) * F * 64;
        Ws = W + (size_t)(2*d - 1) * F * 64;
        bias = b[(2*d - 2)*64 + f] + b[(2*d - 1)*64 + f];
    } else {
        Wr = W + (size_t)20 * F * 64;  // only self matmul; s_rel==0 so Wr term adds 0
        Ws = Wr;
        bias = b[20*64 + f];
    }

    float acc[8];
    #pragma unroll
    for (int a = 0; a < 8; ++a) acc[a] = 0.f;

    constexpr int K4 = (F / 4) * 4;
    for (int k = 0; k < K4; k += 4) {
        float wr0 = Wr[(k+0)*64+f], wr1 = Wr[(k+1)*64+f], wr2 = Wr[(k+2)*64+f], wr3 = Wr[(k+3)*64+f];
        float ws0 = Ws[(k+0)*64+f], ws1 = Ws[(k+1)*64+f], ws2 = Ws[(k+2)*64+f], ws3 = Ws[(k+3)*64+f];
        #pragma unroll
        for (int a = 0; a < 8; ++a) {
            const float4 rv = *(const float4*)&s_rel[w*8 + a][k];
            const float4 sv = *(const float4*)&s_self[w*8 + a][k];
            acc[a] += rv.x*wr0 + rv.y*wr1 + rv.z*wr2 + rv.w*wr3
                    + sv.x*ws0 + sv.y*ws1 + sv.z*ws2 + sv.w*ws3;
        }
    }
    for (int k = K4; k < F; ++k) {
        float wr = Wr[k*64+f], wss = Ws[k*64+f];
        #pragma unroll
        for (int a = 0; a < 8; ++a)
            acc[a] += s_rel[w*8 + a][k]*wr + s_self[w*8 + a][k]*wss;
    }

    const float gf = g[f], bf = beta[f], mf = mean[f];
    const float rf = rsqrtf(var[f] + EPS);
    #pragma unroll
    for (int a = 0; a < 8; ++a) {
        int row = row0 + w*8 + a;
        float t = tanhf(acc[a] + bias);
        out[(size_t)row*64 + f] = gf*(t - mf)*rf + bf;
    }
}

// Pool: out[row][f] = max(h[row][f], max_j h[adj[row][j]][f]); identity for degree 0.
__global__ __launch_bounds__(256)
void pool_kernel(const float* __restrict__ h, float* __restrict__ out, Adj adj)
{
    const int tid = threadIdx.x;
    const int row = blockIdx.x * 4 + (tid >> 6);
    const int f   = tid & 63;
    int d = 0;
    #pragma unroll
    for (int i = 1; i <= 10; ++i) if (row >= d_OFFS[i]) d = i;
    float v = h[(size_t)row*64 + f];
    if (d > 0) {
        const int* ar = adj.p[d-1] + (size_t)(row - d_OFFS[d]) * d;
        for (int j = 0; j < d; ++j) {
            int nr = ar[j];
            v = fmaxf(v, h[(size_t)nr*64 + f]);
        }
    }
    out[(size_t)row*64 + f] = v;
}

// Dense d1 (64->128) + tanh + bn3 + segment sum/max via atomics.
__global__ __launch_bounds__(256)
void dense_seg_kernel(const float* __restrict__ h, const float* __restrict__ W,
                      const float* __restrict__ b,
                      const float* __restrict__ g3, const float* __restrict__ b3,
                      const float* __restrict__ m3, const float* __restrict__ v3,
                      const int* __restrict__ membership,
                      float* __restrict__ segS, float* __restrict__ segM)
{
    __shared__ float s_x[32*64];
    const int tid = threadIdx.x;
    const int row0 = blockIdx.x * 32;
    for (int e = tid; e < 2048; e += 256) s_x[e] = h[(size_t)row0*64 + e];
    __syncthreads();

    const int w = tid >> 6, f = tid & 63;
    float acc0[8], acc1[8];
    #pragma unroll
    for (int a = 0; a < 8; ++a) { acc0[a] = 0.f; acc1[a] = 0.f; }

    for (int k = 0; k < 64; k += 4) {
        float wa0 = W[(k+0)*128+f],    wa1 = W[(k+1)*128+f],    wa2 = W[(k+2)*128+f],    wa3 = W[(k+3)*128+f];
        float wb0 = W[(k+0)*128+64+f], wb1 = W[(k+1)*128+64+f], wb2 = W[(k+2)*128+64+f], wb3 = W[(k+3)*128+64+f];
        #pragma unroll
        for (int a = 0; a < 8; ++a) {
            const float4 xv = *(const float4*)&s_x[(w*8 + a)*64 + k];
            acc0[a] += xv.x*wa0 + xv.y*wa1 + xv.z*wa2 + xv.w*wa3;
            acc1[a] += xv.x*wb0 + xv.y*wb1 + xv.z*wb2 + xv.w*wb3;
        }
    }

    const float gA = g3[f],    bA = b3[f],    mA = m3[f],    rA = rsqrtf(v3[f] + EPS);
    const float gB = g3[64+f], bB = b3[64+f], mB = m3[64+f], rB = rsqrtf(v3[64+f] + EPS);
    const float biasA = b[f], biasB = b[64+f];
    #pragma unroll
    for (int a = 0; a < 8; ++a) {
        int row = row0 + w*8 + a;
        float t0 = tanhf(acc0[a] + biasA);
        float t1 = tanhf(acc1[a] + biasB);
        float h0 = gA*(t0 - mA)*rA + bA;
        float h1 = gB*(t1 - mB)*rB + bB;
        int mol = membership[row];
        atomicAdd(&segS[(size_t)mol*128 + f],      h0);
        atomicAdd(&segS[(size_t)mol*128 + 64 + f], h1);
        atomicMaxF(&segM[(size_t)mol*128 + f],      h0);
        atomicMaxF(&segM[(size_t)mol*128 + 64 + f], h1);
    }
}

// Final: mol = tanh([s m]); model_var = mol@d2_W + d2_b; out = [model_var, x_add]@d3_W + d3_b
__global__ __launch_bounds__(256)
void final_kernel(const float* __restrict__ segS, const float* __restrict__ segM,
                  const float* __restrict__ x_add,
                  const float* __restrict__ d2W, const float* __restrict__ d2b,
                  const float* __restrict__ d3W, const float* __restrict__ d3b,
                  float* __restrict__ out)
{
    const int tid  = threadIdx.x;
    const int mol  = blockIdx.x * 4 + (tid >> 6);
    const int lane = tid & 63;
    const float* s = segS + (size_t)mol * 128;
    const float* m = segM + (size_t)mol * 128;

    float p = tanhf(s[lane])      * d2W[lane]
            + tanhf(s[64 + lane]) * d2W[64 + lane]
            + tanhf(m[lane])      * d2W[128 + lane]
            + tanhf(m[64 + lane]) * d2W[192 + lane];
    #pragma unroll
    for (int o = 32; o > 0; o >>= 1) p += __shfl_down(p, o);

    if (lane == 0) {
        float mv = p + d2b[0];
        float r = mv * d3W[0] + d3b[0];
        for (int i = 0; i < 15; ++i) r += x_add[(size_t)mol*15 + i] * d3W[1 + i];
        out[mol] = r;
    }
}

extern "C" void kernel_launch(void* const* d_in, const int* in_sizes, int n_in,
                              void* d_out, int out_size, void* d_ws, size_t ws_size,
                              hipStream_t stream) {
    const float* atoms      = (const float*)d_in[0];
    const int*   membership = (const int*)  d_in[1];
    Adj adj;
    for (int i = 0; i < 10; ++i) adj.p[i] = (const int*)d_in[2 + i];
    const float* x_add = (const float*)d_in[12];
    const float* gc1_W = (const float*)d_in[13];
    const float* gc1_b = (const float*)d_in[14];
    const float* gc2_W = (const float*)d_in[15];
    const float* gc2_b = (const float*)d_in[16];
    const float* bn1_g = (const float*)d_in[17];
    const float* bn1_b = (const float*)d_in[18];
    const float* bn1_m = (const float*)d_in[19];
    const float* bn1_v = (const float*)d_in[20];
    const float* bn3_g = (const float*)d_in[21];
    const float* bn3_b = (const float*)d_in[22];
    const float* bn3_m = (const float*)d_in[23];
    const float* bn3_v = (const float*)d_in[24];
    const float* d1_W  = (const float*)d_in[25];
    const float* d1_b  = (const float*)d_in[26];
    const float* d2_W  = (const float*)d_in[27];
    const float* d2_b  = (const float*)d_in[28];
    const float* d3_W  = (const float*)d_in[29];
    const float* d3_b  = (const float*)d_in[30];
    float* out = (float*)d_out;

    float* bufA = (float*)d_ws;                       // N_ATOMS x 64
    float* bufB = bufA + (size_t)NATOMS * 64;         // N_ATOMS x 64
    float* segS = bufB + (size_t)NATOMS * 64;         // 4096 x 128
    float* segM = segS + (size_t)BATCH * 128;         // 4096 x 128

    init_seg<<<2048, 256, 0, stream>>>(segS, segM);
    conv_kernel<75,76><<<3840, 256, 0, stream>>>(atoms, gc1_W, gc1_b,
                                                 bn1_g, bn1_b, bn1_m, bn1_v, adj, bufA);
    pool_kernel<<<30720, 256, 0, stream>>>(bufA, bufB, adj);
    conv_kernel<64,64><<<3840, 256, 0, stream>>>(bufB, gc2_W, gc2_b,
                                                 bn1_g, bn1_b, bn1_m, bn1_v, adj, bufA);
    pool_kernel<<<30720, 256, 0, stream>>>(bufA, bufB, adj);
    dense_seg_kernel<<<3840, 256, 0, stream>>>(bufB, d1_W, d1_b,
                                               bn3_g, bn3_b, bn3_m, bn3_v,
                                               membership, segS, segM);
    final_kernel<<<1024, 256, 0, stream>>>(segS, segM, x_add, d2_W, d2_b, d3_W, d3_b, out);
}

// Round 2
// 349.011 us; speedup vs baseline: 1.1932x; 1.1932x over previous
//
#include <hip/hip_runtime.h>
#include <math.h>

#define NATOMS 122880
#define BATCH 4096
#define EPS 1e-3f

// Degree-block offsets (cumsum of COUNTS) and tile (32-atom) cumulative table.
__constant__ int d_OFFS[12] = {0,1024,25600,62464,99328,119808,121856,122368,122624,122752,122816,122880};
__constant__ int d_TCUM[12] = {0,32,800,1952,3104,3744,3808,3824,3832,3836,3838,3840};

struct Adj { const int* p[10]; };

__device__ inline void atomicMaxF(float* addr, float val) {
    if (val >= 0.f) {
        atomicMax((int*)addr, __float_as_int(val == 0.f ? 0.f : val));
    } else {
        atomicMin((unsigned int*)addr, __float_as_uint(val));
    }
}

__global__ __launch_bounds__(256)
void init_seg(float* __restrict__ segS, float* __restrict__ segM) {
    int i = blockIdx.x * 256 + threadIdx.x;   // grid sized exactly 4096*128
    segS[i] = 0.f;
    segM[i] = __int_as_float(0xFF800000);     // -inf
}

__global__ __launch_bounds__(256)
void zero_hist(int* __restrict__ hist) {
    hist[blockIdx.x * 256 + threadIdx.x] = 0;  // grid 16 -> 4096 ints
}

__global__ __launch_bounds__(256)
void hist_kernel(const int* __restrict__ mem, int* __restrict__ hist) {
    int i = blockIdx.x * 256 + threadIdx.x;    // grid 480 -> exactly NATOMS
    atomicAdd(&hist[mem[i]], 1);
}

// Single-block exclusive scan of 4096 ints -> cursor (start offsets).
__global__ __launch_bounds__(1024)
void scan_kernel(const int* __restrict__ hist, int* __restrict__ cursor) {
    __shared__ int s_sums[16];
    const int t = threadIdx.x;
    const int lane = t & 63, wid = t >> 6;
    int4 v = ((const int4*)hist)[t];
    int tot = v.x + v.y + v.z + v.w;
    // inclusive scan of tot within wave
    int x = tot;
    #pragma unroll
    for (int o = 1; o < 64; o <<= 1) { int y = __shfl_up(x, o); if (lane >= o) x += y; }
    if (lane == 63) s_sums[wid] = x;
    __syncthreads();
    if (wid == 0) {
        int y = (lane < 16) ? s_sums[lane] : 0;
        #pragma unroll
        for (int o = 1; o < 16; o <<= 1) { int z = __shfl_up(y, o); if (lane >= o) y += z; }
        if (lane < 16) s_sums[lane] = y;
    }
    __syncthreads();
    int base = (wid > 0 ? s_sums[wid - 1] : 0) + (x - tot);
    int4 c;
    c.x = base;
    c.y = base + v.x;
    c.z = base + v.x + v.y;
    c.w = base + v.x + v.y + v.z;
    ((int4*)cursor)[t] = c;
}

__global__ __launch_bounds__(256)
void scatter_kernel(const int* __restrict__ mem, int* __restrict__ cursor,
                    int* __restrict__ sidx) {
    int i = blockIdx.x * 256 + threadIdx.x;    // grid 480
    int m = mem[i];
    int p = atomicAdd(&cursor[m], 1);
    sidx[p] = i;
}

// Graph conv for one 32-atom tile of a single degree block.
template<int F, int FPAD>
__global__ __launch_bounds__(256)
void conv_kernel(const float* __restrict__ x, const float* __restrict__ W,
                 const float* __restrict__ b,
                 const float* __restrict__ g, const float* __restrict__ beta,
                 const float* __restrict__ mean, const float* __restrict__ var,
                 Adj adj, float* __restrict__ out)
{
    __shared__ float s_self[32][FPAD];
    __shared__ float s_rel[32][FPAD];
    __shared__ int   s_adj[320];

    const int tid = threadIdx.x;
    const int bx  = blockIdx.x;
    int d = 0;
    #pragma unroll
    for (int i = 1; i <= 10; ++i) if (bx >= d_TCUM[i]) d = i;
    const int tile = bx - d_TCUM[d];
    const int row0 = d_OFFS[d] + tile * 32;

    if (d > 0) {
        const int* ap = adj.p[d-1] + (size_t)tile * 32 * d;
        for (int e = tid; e < 32 * d; e += 256) s_adj[e] = ap[e];
    }
    __syncthreads();

    for (int e = tid; e < 32 * F; e += 256) {
        int a = e / F, k = e - a * F;
        s_self[a][k] = x[(size_t)(row0 + a) * F + k];
        float sum = 0.f;
        for (int j = 0; j < d; ++j) sum += x[(size_t)s_adj[a*d + j] * F + k];
        s_rel[a][k] = sum;
    }
    __syncthreads();

    const int w = tid >> 6, f = tid & 63;
    const float* Wr; const float* Ws; float bias;
    if (d > 0) {
        Wr = W + (size_t)(2*d - 2) * F * 64;
        Ws = W + (size_t)(2*d - 1) * F * 64;
        bias = b[(2*d - 2)*64 + f] + b[(2*d - 1)*64 + f];
    } else {
        Wr = W + (size_t)20 * F * 64;
        Ws = Wr;
        bias = b[20*64 + f];
    }

    float acc[8];
    #pragma unroll
    for (int a = 0; a < 8; ++a) acc[a] = 0.f;

    constexpr int K4 = (F / 4) * 4;
    for (int k = 0; k < K4; k += 4) {
        float wr0 = Wr[(k+0)*64+f], wr1 = Wr[(k+1)*64+f], wr2 = Wr[(k+2)*64+f], wr3 = Wr[(k+3)*64+f];
        float ws0 = Ws[(k+0)*64+f], ws1 = Ws[(k+1)*64+f], ws2 = Ws[(k+2)*64+f], ws3 = Ws[(k+3)*64+f];
        #pragma unroll
        for (int a = 0; a < 8; ++a) {
            const float4 rv = *(const float4*)&s_rel[w*8 + a][k];
            const float4 sv = *(const float4*)&s_self[w*8 + a][k];
            acc[a] += rv.x*wr0 + rv.y*wr1 + rv.z*wr2 + rv.w*wr3
                    + sv.x*ws0 + sv.y*ws1 + sv.z*ws2 + sv.w*ws3;
        }
    }
    for (int k = K4; k < F; ++k) {
        float wr = Wr[k*64+f], wss = Ws[k*64+f];
        #pragma unroll
        for (int a = 0; a < 8; ++a)
            acc[a] += s_rel[w*8 + a][k]*wr + s_self[w*8 + a][k]*wss;
    }

    const float gf = g[f], bf = beta[f], mf = mean[f];
    const float rf = rsqrtf(var[f] + EPS);
    #pragma unroll
    for (int a = 0; a < 8; ++a) {
        int row = row0 + w*8 + a;
        float t = tanhf(acc[a] + bias);
        out[(size_t)row*64 + f] = gf*(t - mf)*rf + bf;
    }
}

// Pool: out[row][f] = max(h[row][f], max_j h[adj[row][j]][f]); identity for degree 0.
__global__ __launch_bounds__(256)
void pool_kernel(const float* __restrict__ h, float* __restrict__ out, Adj adj)
{
    const int tid = threadIdx.x;
    const int row = blockIdx.x * 4 + (tid >> 6);
    const int f   = tid & 63;
    int d = 0;
    #pragma unroll
    for (int i = 1; i <= 10; ++i) if (row >= d_OFFS[i]) d = i;
    float v = h[(size_t)row*64 + f];
    if (d > 0) {
        const int* ar = adj.p[d-1] + (size_t)(row - d_OFFS[d]) * d;
        for (int j = 0; j < d; ++j) {
            int nr = ar[j];
            v = fmaxf(v, h[(size_t)nr*64 + f]);
        }
    }
    out[(size_t)row*64 + f] = v;
}

// Dense d1 (64->128) + tanh + bn3 + segment sum/max over SORTED atoms.
// Per-thread segmented run-reduction cuts atomics ~12x vs per-row atomics.
__global__ __launch_bounds__(256)
void dense_seg_sorted(const float* __restrict__ h, const float* __restrict__ W,
                      const float* __restrict__ b,
                      const float* __restrict__ g3, const float* __restrict__ b3,
                      const float* __restrict__ m3, const float* __restrict__ v3,
                      const int* __restrict__ membership,
                      const int* __restrict__ sidx,
                      float* __restrict__ segS, float* __restrict__ segM)
{
    __shared__ float s_x[32*64];
    __shared__ int s_mol[32];
    const int tid = threadIdx.x;
    const int row0 = blockIdx.x * 32;

    __shared__ int s_ridx[32];
    if (tid < 32) {
        int r = sidx[row0 + tid];
        s_ridx[tid] = r;
        s_mol[tid] = membership[r];
    }
    __syncthreads();
    for (int e = tid; e < 2048; e += 256) {
        int a = e >> 6, k = e & 63;
        s_x[e] = h[(size_t)s_ridx[a]*64 + k];
    }
    __syncthreads();

    const int w = tid >> 6, f = tid & 63;
    float acc0[8], acc1[8];
    #pragma unroll
    for (int a = 0; a < 8; ++a) { acc0[a] = 0.f; acc1[a] = 0.f; }

    for (int k = 0; k < 64; k += 4) {
        float wa0 = W[(k+0)*128+f],    wa1 = W[(k+1)*128+f],    wa2 = W[(k+2)*128+f],    wa3 = W[(k+3)*128+f];
        float wb0 = W[(k+0)*128+64+f], wb1 = W[(k+1)*128+64+f], wb2 = W[(k+2)*128+64+f], wb3 = W[(k+3)*128+64+f];
        #pragma unroll
        for (int a = 0; a < 8; ++a) {
            const float4 xv = *(const float4*)&s_x[(w*8 + a)*64 + k];
            acc0[a] += xv.x*wa0 + xv.y*wa1 + xv.z*wa2 + xv.w*wa3;
            acc1[a] += xv.x*wb0 + xv.y*wb1 + xv.z*wb2 + xv.w*wb3;
        }
    }

    const float gA = g3[f],    bA = b3[f],    mA = m3[f],    rA = rsqrtf(v3[f] + EPS);
    const float gB = g3[64+f], bB = b3[64+f], mB = m3[64+f], rB = rsqrtf(v3[64+f] + EPS);
    const float biasA = b[f], biasB = b[64+f];

    int prev = -1;
    float s0 = 0.f, s1 = 0.f, m0 = 0.f, m1 = 0.f;
    #pragma unroll
    for (int a = 0; a < 8; ++a) {
        float t0 = tanhf(acc0[a] + biasA);
        float t1 = tanhf(acc1[a] + biasB);
        float h0 = gA*(t0 - mA)*rA + bA;
        float h1 = gB*(t1 - mB)*rB + bB;
        int mol = s_mol[w*8 + a];
        if (mol != prev) {
            if (prev >= 0) {
                atomicAdd(&segS[(size_t)prev*128 + f],      s0);
                atomicAdd(&segS[(size_t)prev*128 + 64 + f], s1);
                atomicMaxF(&segM[(size_t)prev*128 + f],      m0);
                atomicMaxF(&segM[(size_t)prev*128 + 64 + f], m1);
            }
            prev = mol; s0 = h0; s1 = h1; m0 = h0; m1 = h1;
        } else {
            s0 += h0; s1 += h1; m0 = fmaxf(m0, h0); m1 = fmaxf(m1, h1);
        }
    }
    atomicAdd(&segS[(size_t)prev*128 + f],      s0);
    atomicAdd(&segS[(size_t)prev*128 + 64 + f], s1);
    atomicMaxF(&segM[(size_t)prev*128 + f],      m0);
    atomicMaxF(&segM[(size_t)prev*128 + 64 + f], m1);
}

// Final: mol = tanh([s m]); model_var = mol@d2_W + d2_b; out = [model_var, x_add]@d3_W + d3_b
__global__ __launch_bounds__(256)
void final_kernel(const float* __restrict__ segS, const float* __restrict__ segM,
                  const float* __restrict__ x_add,
                  const float* __restrict__ d2W, const float* __restrict__ d2b,
                  const float* __restrict__ d3W, const float* __restrict__ d3b,
                  float* __restrict__ out)
{
    const int tid  = threadIdx.x;
    const int mol  = blockIdx.x * 4 + (tid >> 6);
    const int lane = tid & 63;
    const float* s = segS + (size_t)mol * 128;
    const float* m = segM + (size_t)mol * 128;

    float p = tanhf(s[lane])      * d2W[lane]
            + tanhf(s[64 + lane]) * d2W[64 + lane]
            + tanhf(m[lane])      * d2W[128 + lane]
            + tanhf(m[64 + lane]) * d2W[192 + lane];
    #pragma unroll
    for (int o = 32; o > 0; o >>= 1) p += __shfl_down(p, o);

    if (lane == 0) {
        float mv = p + d2b[0];
        float r = mv * d3W[0] + d3b[0];
        for (int i = 0; i < 15; ++i) r += x_add[(size_t)mol*15 + i] * d3W[1 + i];
        out[mol] = r;
    }
}

extern "C" void kernel_launch(void* const* d_in, const int* in_sizes, int n_in,
                              void* d_out, int out_size, void* d_ws, size_t ws_size,
                              hipStream_t stream) {
    const float* atoms      = (const float*)d_in[0];
    const int*   membership = (const int*)  d_in[1];
    Adj adj;
    for (int i = 0; i < 10; ++i) adj.p[i] = (const int*)d_in[2 + i];
    const float* x_add = (const float*)d_in[12];
    const float* gc1_W = (const float*)d_in[13];
    const float* gc1_b = (const float*)d_in[14];
    const float* gc2_W = (const float*)d_in[15];
    const float* gc2_b = (const float*)d_in[16];
    const float* bn1_g = (const float*)d_in[17];
    const float* bn1_b = (const float*)d_in[18];
    const float* bn1_m = (const float*)d_in[19];
    const float* bn1_v = (const float*)d_in[20];
    const float* bn3_g = (const float*)d_in[21];
    const float* bn3_b = (const float*)d_in[22];
    const float* bn3_m = (const float*)d_in[23];
    const float* bn3_v = (const float*)d_in[24];
    const float* d1_W  = (const float*)d_in[25];
    const float* d1_b  = (const float*)d_in[26];
    const float* d2_W  = (const float*)d_in[27];
    const float* d2_b  = (const float*)d_in[28];
    const float* d3_W  = (const float*)d_in[29];
    const float* d3_b  = (const float*)d_in[30];
    float* out = (float*)d_out;

    float* bufA = (float*)d_ws;                       // N_ATOMS x 64
    float* bufB = bufA + (size_t)NATOMS * 64;         // N_ATOMS x 64
    float* segS = bufB + (size_t)NATOMS * 64;         // 4096 x 128
    float* segM = segS + (size_t)BATCH * 128;         // 4096 x 128

    // Sort scratch reuses bufA region (bufA is dead after pool2 reads it;
    // the sort chain runs after pool2 so there is no overlap).
    int* sidx   = (int*)bufA;                         // N_ATOMS ints
    int* hist   = sidx + NATOMS;                      // 4096 ints
    int* cursor = hist + BATCH;                       // 4096 ints

    conv_kernel<75,76><<<3840, 256, 0, stream>>>(atoms, gc1_W, gc1_b,
                                                 bn1_g, bn1_b, bn1_m, bn1_v, adj, bufA);
    pool_kernel<<<30720, 256, 0, stream>>>(bufA, bufB, adj);
    conv_kernel<64,64><<<3840, 256, 0, stream>>>(bufB, gc2_W, gc2_b,
                                                 bn1_g, bn1_b, bn1_m, bn1_v, adj, bufA);
    pool_kernel<<<30720, 256, 0, stream>>>(bufA, bufB, adj);

    // bufA now dead -> build molecule-sorted atom index in its space.
    zero_hist<<<16, 256, 0, stream>>>(hist);
    hist_kernel<<<480, 256, 0, stream>>>(membership, hist);
    scan_kernel<<<1, 1024, 0, stream>>>(hist, cursor);
    scatter_kernel<<<480, 256, 0, stream>>>(membership, cursor, sidx);
    init_seg<<<2048, 256, 0, stream>>>(segS, segM);

    dense_seg_sorted<<<3840, 256, 0, stream>>>(bufB, d1_W, d1_b,
                                               bn3_g, bn3_b, bn3_m, bn3_v,
                                               membership, sidx, segS, segM);
    final_kernel<<<1024, 256, 0, stream>>>(segS, segM, x_add, d2_W, d2_b, d3_W, d3_b, out);
}

// Round 3
// 248.026 us; speedup vs baseline: 1.6790x; 1.4072x over previous
//
#include <hip/hip_runtime.h>
#include <math.h>

#define NATOMS 122880
#define BATCH 4096
#define EPS 1e-3f

// Degree-block offsets (cumsum of COUNTS) and tile (32-atom) cumulative table.
__constant__ int d_OFFS[12] = {0,1024,25600,62464,99328,119808,121856,122368,122624,122752,122816,122880};
__constant__ int d_TCUM[12] = {0,32,800,1952,3104,3744,3808,3824,3832,3836,3838,3840};

struct Adj { const int* p[10]; };

typedef __attribute__((ext_vector_type(8))) short bf16x8;
typedef __attribute__((ext_vector_type(4))) float f32x4;

__device__ inline float bf2f(ushort u) { return __uint_as_float(((unsigned)u) << 16); }
__device__ inline ushort f2bf(float f) {
    unsigned u = __float_as_uint(f);
    return (ushort)((u + 0x7fffu + ((u >> 16) & 1u)) >> 16);   // RNE
}

__device__ inline void atomicMaxF(float* addr, float val) {
    if (val >= 0.f) {
        atomicMax((int*)addr, __float_as_int(val == 0.f ? 0.f : val));
    } else {
        atomicMin((unsigned int*)addr, __float_as_uint(val));
    }
}

// ---------------- pre-pass kernels ----------------

__global__ __launch_bounds__(256)
void cvt_x(const float* __restrict__ x, ushort* __restrict__ xb) {
    int i = (blockIdx.x * 256 + threadIdx.x) * 4;   // grid 9000 -> 9,216,000 elems
    float4 v = *(const float4*)&x[i];
    unsigned lo = f2bf(v.x) | ((unsigned)f2bf(v.y) << 16);
    unsigned hi = f2bf(v.z) | ((unsigned)f2bf(v.w) << 16);
    uint2 p; p.x = lo; p.y = hi;
    *(uint2*)&xb[i] = p;
}

// Build per-degree stacked+transposed bf16 weights:
// Wt1[d][64][160]: k<75 -> Wr[k][n] (d==0: 0), k<150 -> Ws[k-75][n] (d==0: W20), else 0
// Wt2[d][64][128]: k<64 -> Wr[k][n] (d==0: 0), else Ws[k-64][n] (d==0: W20)
__global__ __launch_bounds__(256)
void build_wt(const float* __restrict__ W1, const float* __restrict__ W2,
              ushort* __restrict__ Wt1, ushort* __restrict__ Wt2) {
    int idx = blockIdx.x * 256 + threadIdx.x;       // grid 792 -> 202,752
    if (idx < 112640) {
        int m = idx / 10240;
        int rem = idx - m * 10240;
        int n = rem / 160, k = rem - n * 160;
        float v;
        if (k < 75)       v = (m == 0) ? 0.f : W1[(size_t)(2*m-2)*75*64 + k*64 + n];
        else if (k < 150) v = (m == 0) ? W1[(size_t)20*75*64 + (k-75)*64 + n]
                                       : W1[(size_t)(2*m-1)*75*64 + (k-75)*64 + n];
        else              v = 0.f;
        Wt1[(size_t)m*10240 + n*160 + k] = f2bf(v);
    } else {
        int i2 = idx - 112640;
        int m = i2 / 8192;
        int rem = i2 - m * 8192;
        int n = rem / 128, k = rem - n * 128;
        float v;
        if (k < 64) v = (m == 0) ? 0.f : W2[(size_t)(2*m-2)*64*64 + k*64 + n];
        else        v = (m == 0) ? W2[(size_t)20*64*64 + (k-64)*64 + n]
                                 : W2[(size_t)(2*m-1)*64*64 + (k-64)*64 + n];
        Wt2[(size_t)m*8192 + n*128 + k] = f2bf(v);
    }
}

__global__ __launch_bounds__(256)
void init_seg(float* __restrict__ segS, float* __restrict__ segM) {
    int i = blockIdx.x * 256 + threadIdx.x;   // grid 2048 -> 4096*128
    segS[i] = 0.f;
    segM[i] = __int_as_float(0xFF800000);     // -inf
}

__global__ __launch_bounds__(256)
void zero_hist(int* __restrict__ hist) {
    hist[blockIdx.x * 256 + threadIdx.x] = 0;  // grid 16
}

__global__ __launch_bounds__(256)
void hist_kernel(const int* __restrict__ mem, int* __restrict__ hist) {
    int i = blockIdx.x * 256 + threadIdx.x;    // grid 480
    atomicAdd(&hist[mem[i]], 1);
}

__global__ __launch_bounds__(1024)
void scan_kernel(const int* __restrict__ hist, int* __restrict__ cursor) {
    __shared__ int s_sums[16];
    const int t = threadIdx.x;
    const int lane = t & 63, wid = t >> 6;
    int4 v = ((const int4*)hist)[t];
    int tot = v.x + v.y + v.z + v.w;
    int x = tot;
    #pragma unroll
    for (int o = 1; o < 64; o <<= 1) { int y = __shfl_up(x, o); if (lane >= o) x += y; }
    if (lane == 63) s_sums[wid] = x;
    __syncthreads();
    if (wid == 0) {
        int y = (lane < 16) ? s_sums[lane] : 0;
        #pragma unroll
        for (int o = 1; o < 16; o <<= 1) { int z = __shfl_up(y, o); if (lane >= o) y += z; }
        if (lane < 16) s_sums[lane] = y;
    }
    __syncthreads();
    int base = (wid > 0 ? s_sums[wid - 1] : 0) + (x - tot);
    int4 c;
    c.x = base; c.y = base + v.x; c.z = base + v.x + v.y; c.w = base + v.x + v.y + v.z;
    ((int4*)cursor)[t] = c;
}

__global__ __launch_bounds__(256)
void scatter_kernel(const int* __restrict__ mem, int* __restrict__ cursor,
                    int* __restrict__ sidx) {
    int i = blockIdx.x * 256 + threadIdx.x;    // grid 480
    int m = mem[i];
    int p = atomicAdd(&cursor[m], 1);
    sidx[p] = i;
}

// ---------------- conv (MFMA) ----------------

template<int F, int KPAD, int D>
__device__ inline void stage_rows(ushort (*s_A)[KPAD], const int* __restrict__ s_adj,
                                  const ushort* __restrict__ xb, int row0, int w, int lane)
{
    constexpr int PADW = KPAD - 2 * F;
    #pragma unroll
    for (int i = 0; i < 8; ++i) {
        const int a = w * 8 + i;
        const int* ar = s_adj + a * D;
        {
            float s = 0.f;
            #pragma unroll
            for (int j = 0; j < D; ++j) s += bf2f(xb[(size_t)ar[j] * F + lane]);
            s_A[a][lane]     = f2bf(s);
            s_A[a][F + lane] = xb[(size_t)(row0 + a) * F + lane];
        }
        if constexpr (F > 64) {
            if (lane < F - 64) {
                const int k = 64 + lane;
                float s = 0.f;
                #pragma unroll
                for (int j = 0; j < D; ++j) s += bf2f(xb[(size_t)ar[j] * F + k]);
                s_A[a][k]     = f2bf(s);
                s_A[a][F + k] = xb[(size_t)(row0 + a) * F + k];
            }
        }
        if (lane < PADW) s_A[a][2 * F + lane] = 0;
    }
}

// One 32-atom tile. A = [relsum | self] (K=2F, padded to KTOT), B = Wt[d] (64 x KTOT).
// out = bf16( bn( tanh( A@B + bias ) ) )
template<int F, int KTOT, int KPAD>
__global__ __launch_bounds__(256)
void conv_mfma(const ushort* __restrict__ xb, const ushort* __restrict__ Wt,
               const float* __restrict__ b,
               const float* __restrict__ g, const float* __restrict__ beta,
               const float* __restrict__ mean, const float* __restrict__ var,
               Adj adj, ushort* __restrict__ out)
{
    __shared__ ushort s_A[32][KPAD];
    __shared__ int s_adj[320];

    const int tid = threadIdx.x;
    const int bx  = blockIdx.x;
    int d = 0;
    #pragma unroll
    for (int i = 1; i <= 10; ++i) if (bx >= d_TCUM[i]) d = i;
    const int tile = bx - d_TCUM[d];
    const int row0 = d_OFFS[d] + tile * 32;

    if (d > 0) {
        const int* ap = adj.p[d-1] + (size_t)tile * 32 * d;
        for (int e = tid; e < 32 * d; e += 256) s_adj[e] = ap[e];
    }
    __syncthreads();

    const int w = tid >> 6, lane = tid & 63;
    switch (d) {
        case 0:  stage_rows<F,KPAD,0 >(s_A, s_adj, xb, row0, w, lane); break;
        case 1:  stage_rows<F,KPAD,1 >(s_A, s_adj, xb, row0, w, lane); break;
        case 2:  stage_rows<F,KPAD,2 >(s_A, s_adj, xb, row0, w, lane); break;
        case 3:  stage_rows<F,KPAD,3 >(s_A, s_adj, xb, row0, w, lane); break;
        case 4:  stage_rows<F,KPAD,4 >(s_A, s_adj, xb, row0, w, lane); break;
        case 5:  stage_rows<F,KPAD,5 >(s_A, s_adj, xb, row0, w, lane); break;
        case 6:  stage_rows<F,KPAD,6 >(s_A, s_adj, xb, row0, w, lane); break;
        case 7:  stage_rows<F,KPAD,7 >(s_A, s_adj, xb, row0, w, lane); break;
        case 8:  stage_rows<F,KPAD,8 >(s_A, s_adj, xb, row0, w, lane); break;
        case 9:  stage_rows<F,KPAD,9 >(s_A, s_adj, xb, row0, w, lane); break;
        default: stage_rows<F,KPAD,10>(s_A, s_adj, xb, row0, w, lane); break;
    }
    __syncthreads();

    // wave w: row-tile r = w&1 (16 atoms), col pair c = w>>1 (2x16 cols)
    const int r = w & 1, c = w >> 1;
    const int l15 = lane & 15, lg = lane >> 4;
    const int kgrp = lg * 8;

    f32x4 acc0 = {}, acc1 = {};
    const ushort* ap0 = &s_A[r * 16 + l15][kgrp];
    const ushort* wt0 = Wt + ((size_t)d * 64 + c * 32 + l15) * KTOT + kgrp;
    const ushort* wt1 = wt0 + 16 * KTOT;
    #pragma unroll
    for (int ks = 0; ks < KTOT / 32; ++ks) {
        bf16x8 af = *(const bf16x8*)(ap0 + ks * 32);
        bf16x8 b0 = *(const bf16x8*)(wt0 + ks * 32);
        bf16x8 b1 = *(const bf16x8*)(wt1 + ks * 32);
        acc0 = __builtin_amdgcn_mfma_f32_16x16x32_bf16(af, b0, acc0, 0, 0, 0);
        acc1 = __builtin_amdgcn_mfma_f32_16x16x32_bf16(af, b1, acc1, 0, 0, 0);
    }

    // epilogue: bias + tanh + bn, store bf16
    const int col0 = c * 32 + l15;
    const int col1 = col0 + 16;
    float bias0, bias1;
    if (d > 0) {
        bias0 = b[(2*d-2)*64 + col0] + b[(2*d-1)*64 + col0];
        bias1 = b[(2*d-2)*64 + col1] + b[(2*d-1)*64 + col1];
    } else {
        bias0 = b[20*64 + col0];
        bias1 = b[20*64 + col1];
    }
    const float g0 = g[col0], be0 = beta[col0], m0 = mean[col0], r0 = rsqrtf(var[col0] + EPS);
    const float g1 = g[col1], be1 = beta[col1], m1 = mean[col1], r1 = rsqrtf(var[col1] + EPS);
    const int rbase = row0 + r * 16 + lg * 4;
    #pragma unroll
    for (int i = 0; i < 4; ++i) {
        float t0 = tanhf(acc0[i] + bias0);
        float t1 = tanhf(acc1[i] + bias1);
        out[(size_t)(rbase + i) * 64 + col0] = f2bf(g0 * (t0 - m0) * r0 + be0);
        out[(size_t)(rbase + i) * 64 + col1] = f2bf(g1 * (t1 - m1) * r1 + be1);
    }
}

// ---------------- pool (bf16) ----------------

__global__ __launch_bounds__(256)
void pool_kernel(const ushort* __restrict__ h, ushort* __restrict__ out, Adj adj)
{
    const int tid = threadIdx.x;
    const int row = blockIdx.x * 4 + (tid >> 6);
    const int f   = tid & 63;
    int d = 0;
    #pragma unroll
    for (int i = 1; i <= 10; ++i) if (row >= d_OFFS[i]) d = i;
    float v = bf2f(h[(size_t)row * 64 + f]);
    if (d > 0) {
        const int* ar = adj.p[d-1] + (size_t)(row - d_OFFS[d]) * d;
        #define POOLD(D) { _Pragma("unroll") for (int j = 0; j < D; ++j) \
                             v = fmaxf(v, bf2f(h[(size_t)ar[j] * 64 + f])); }
        switch (d) {
            case 1:  POOLD(1)  break;
            case 2:  POOLD(2)  break;
            case 3:  POOLD(3)  break;
            case 4:  POOLD(4)  break;
            case 5:  POOLD(5)  break;
            case 6:  POOLD(6)  break;
            case 7:  POOLD(7)  break;
            case 8:  POOLD(8)  break;
            case 9:  POOLD(9)  break;
            default: POOLD(10) break;
        }
        #undef POOLD
    }
    out[(size_t)row * 64 + f] = f2bf(v);   // exact: v is an existing bf16 value
}

// ---------------- dense d1 + segment reduce (sorted atoms) ----------------

__global__ __launch_bounds__(256)
void dense_seg_sorted(const ushort* __restrict__ h, const float* __restrict__ W,
                      const float* __restrict__ b,
                      const float* __restrict__ g3, const float* __restrict__ b3,
                      const float* __restrict__ m3, const float* __restrict__ v3,
                      const int* __restrict__ membership,
                      const int* __restrict__ sidx,
                      float* __restrict__ segS, float* __restrict__ segM)
{
    __shared__ float s_x[32*64];
    __shared__ int s_mol[32];
    __shared__ int s_ridx[32];
    const int tid = threadIdx.x;
    const int row0 = blockIdx.x * 32;

    if (tid < 32) {
        int r = sidx[row0 + tid];
        s_ridx[tid] = r;
        s_mol[tid] = membership[r];
    }
    __syncthreads();
    for (int e = tid; e < 2048; e += 256) {
        int a = e >> 6, k = e & 63;
        s_x[e] = bf2f(h[(size_t)s_ridx[a] * 64 + k]);
    }
    __syncthreads();

    const int w = tid >> 6, f = tid & 63;
    float acc0[8], acc1[8];
    #pragma unroll
    for (int a = 0; a < 8; ++a) { acc0[a] = 0.f; acc1[a] = 0.f; }

    for (int k = 0; k < 64; k += 4) {
        float wa0 = W[(k+0)*128+f],    wa1 = W[(k+1)*128+f],    wa2 = W[(k+2)*128+f],    wa3 = W[(k+3)*128+f];
        float wb0 = W[(k+0)*128+64+f], wb1 = W[(k+1)*128+64+f], wb2 = W[(k+2)*128+64+f], wb3 = W[(k+3)*128+64+f];
        #pragma unroll
        for (int a = 0; a < 8; ++a) {
            const float4 xv = *(const float4*)&s_x[(w*8 + a)*64 + k];
            acc0[a] += xv.x*wa0 + xv.y*wa1 + xv.z*wa2 + xv.w*wa3;
            acc1[a] += xv.x*wb0 + xv.y*wb1 + xv.z*wb2 + xv.w*wb3;
        }
    }

    const float gA = g3[f],    bA = b3[f],    mA = m3[f],    rA = rsqrtf(v3[f] + EPS);
    const float gB = g3[64+f], bB = b3[64+f], mB = m3[64+f], rB = rsqrtf(v3[64+f] + EPS);
    const float biasA = b[f], biasB = b[64+f];

    int prev = -1;
    float s0 = 0.f, s1 = 0.f, mm0 = 0.f, mm1 = 0.f;
    #pragma unroll
    for (int a = 0; a < 8; ++a) {
        float t0 = tanhf(acc0[a] + biasA);
        float t1 = tanhf(acc1[a] + biasB);
        float h0 = gA*(t0 - mA)*rA + bA;
        float h1 = gB*(t1 - mB)*rB + bB;
        int mol = s_mol[w*8 + a];
        if (mol != prev) {
            if (prev >= 0) {
                atomicAdd(&segS[(size_t)prev*128 + f],      s0);
                atomicAdd(&segS[(size_t)prev*128 + 64 + f], s1);
                atomicMaxF(&segM[(size_t)prev*128 + f],      mm0);
                atomicMaxF(&segM[(size_t)prev*128 + 64 + f], mm1);
            }
            prev = mol; s0 = h0; s1 = h1; mm0 = h0; mm1 = h1;
        } else {
            s0 += h0; s1 += h1; mm0 = fmaxf(mm0, h0); mm1 = fmaxf(mm1, h1);
        }
    }
    atomicAdd(&segS[(size_t)prev*128 + f],      s0);
    atomicAdd(&segS[(size_t)prev*128 + 64 + f], s1);
    atomicMaxF(&segM[(size_t)prev*128 + f],      mm0);
    atomicMaxF(&segM[(size_t)prev*128 + 64 + f], mm1);
}

// ---------------- final ----------------

__global__ __launch_bounds__(256)
void final_kernel(const float* __restrict__ segS, const float* __restrict__ segM,
                  const float* __restrict__ x_add,
                  const float* __restrict__ d2W, const float* __restrict__ d2b,
                  const float* __restrict__ d3W, const float* __restrict__ d3b,
                  float* __restrict__ out)
{
    const int tid  = threadIdx.x;
    const int mol  = blockIdx.x * 4 + (tid >> 6);
    const int lane = tid & 63;
    const float* s = segS + (size_t)mol * 128;
    const float* m = segM + (size_t)mol * 128;

    float p = tanhf(s[lane])      * d2W[lane]
            + tanhf(s[64 + lane]) * d2W[64 + lane]
            + tanhf(m[lane])      * d2W[128 + lane]
            + tanhf(m[64 + lane]) * d2W[192 + lane];
    #pragma unroll
    for (int o = 32; o > 0; o >>= 1) p += __shfl_down(p, o);

    if (lane == 0) {
        float mv = p + d2b[0];
        float r = mv * d3W[0] + d3b[0];
        for (int i = 0; i < 15; ++i) r += x_add[(size_t)mol*15 + i] * d3W[1 + i];
        out[mol] = r;
    }
}

extern "C" void kernel_launch(void* const* d_in, const int* in_sizes, int n_in,
                              void* d_out, int out_size, void* d_ws, size_t ws_size,
                              hipStream_t stream) {
    const float* atoms      = (const float*)d_in[0];
    const int*   membership = (const int*)  d_in[1];
    Adj adj;
    for (int i = 0; i < 10; ++i) adj.p[i] = (const int*)d_in[2 + i];
    const float* x_add = (const float*)d_in[12];
    const float* gc1_W = (const float*)d_in[13];
    const float* gc1_b = (const float*)d_in[14];
    const float* gc2_W = (const float*)d_in[15];
    const float* gc2_b = (const float*)d_in[16];
    const float* bn1_g = (const float*)d_in[17];
    const float* bn1_b = (const float*)d_in[18];
    const float* bn1_m = (const float*)d_in[19];
    const float* bn1_v = (const float*)d_in[20];
    const float* bn3_g = (const float*)d_in[21];
    const float* bn3_b = (const float*)d_in[22];
    const float* bn3_m = (const float*)d_in[23];
    const float* bn3_v = (const float*)d_in[24];
    const float* d1_W  = (const float*)d_in[25];
    const float* d1_b  = (const float*)d_in[26];
    const float* d2_W  = (const float*)d_in[27];
    const float* d2_b  = (const float*)d_in[28];
    const float* d3_W  = (const float*)d_in[29];
    const float* d3_b  = (const float*)d_in[30];
    float* out = (float*)d_out;

    // ---- workspace layout (bytes) ----
    ushort* xb  = (ushort*)d_ws;                       // 9,216,000
    ushort* hA  = xb  + (size_t)9216000;               // 7,864,320
    ushort* hB  = hA  + (size_t)7864320;               // 7,864,320
    ushort* Wt1 = hB  + (size_t)7864320;               // 112,640
    ushort* Wt2 = Wt1 + (size_t)112640;                // 90,112
    float* segS = (float*)(Wt2 + (size_t)90112);       // 4096*128
    float* segM = segS + (size_t)BATCH * 128;          // 4096*128
    int*   sidx = (int*)(segM + (size_t)BATCH * 128);  // NATOMS
    int*   hist = sidx + NATOMS;                       // 4096
    int* cursor = hist + BATCH;                        // 4096

    // pre-pass (independent of conv outputs)
    cvt_x<<<9000, 256, 0, stream>>>(atoms, xb);
    build_wt<<<792, 256, 0, stream>>>(gc1_W, gc2_W, Wt1, Wt2);
    zero_hist<<<16, 256, 0, stream>>>(hist);
    hist_kernel<<<480, 256, 0, stream>>>(membership, hist);
    scan_kernel<<<1, 1024, 0, stream>>>(hist, cursor);
    scatter_kernel<<<480, 256, 0, stream>>>(membership, cursor, sidx);
    init_seg<<<2048, 256, 0, stream>>>(segS, segM);

    // main pipeline
    conv_mfma<75,160,168><<<3840, 256, 0, stream>>>(xb, Wt1, gc1_b,
                                                    bn1_g, bn1_b, bn1_m, bn1_v, adj, hA);
    pool_kernel<<<30720, 256, 0, stream>>>(hA, hB, adj);
    conv_mfma<64,128,136><<<3840, 256, 0, stream>>>(hB, Wt2, gc2_b,
                                                    bn1_g, bn1_b, bn1_m, bn1_v, adj, hA);
    pool_kernel<<<30720, 256, 0, stream>>>(hA, hB, adj);
    dense_seg_sorted<<<3840, 256, 0, stream>>>(hB, d1_W, d1_b,
                                               bn3_g, bn3_b, bn3_m, bn3_v,
                                               membership, sidx, segS, segM);
    final_kernel<<<1024, 256, 0, stream>>>(segS, segM, x_add, d2_W, d2_b, d3_W, d3_b, out);
}